// Round 2
// baseline (9864.257 us; speedup 1.0000x reference)
//
#include <hip/hip_runtime.h>
#include <hip/hip_bf16.h>

#define NB 128
#define LSEQ 512
#define HD 512
#define G3 1536
#define TI 64
#define KC 16
#define MAX_DEPTH 64

// ---------------------------------------------------------------------------
// prep: transpose W_ih, W_hh -> [k][3H], combine biases
// ---------------------------------------------------------------------------
__global__ __launch_bounds__(256) void prep_kernel(
    const float* __restrict__ W_ih, const float* __restrict__ W_hh,
    const float* __restrict__ b_ih, const float* __restrict__ b_hh,
    float* __restrict__ Wt_ih, float* __restrict__ Wt_hh,
    float* __restrict__ bias4)
{
    int idx = blockIdx.x * 256 + threadIdx.x;
    if (idx < HD * G3) {
        int k = idx / G3, g = idx % G3;
        Wt_ih[idx] = W_ih[g * HD + k];
        Wt_hh[idx] = W_hh[g * HD + k];
    }
    if (idx < HD) {
        bias4[idx]        = b_ih[idx]        + b_hh[idx];         // r
        bias4[512 + idx]  = b_ih[512 + idx]  + b_hh[512 + idx];   // z
        bias4[1024 + idx] = b_ih[1024 + idx];                     // n (x side)
        bias4[1536 + idx] = b_hh[1024 + idx];                     // n (h side)
    }
}

// ---------------------------------------------------------------------------
// sched: compute depth of every (n,l), bucket items by depth.
// depth = distance since last is_initial==1 (is_initial applies at step start).
// One block, 128 threads (one per batch row).
// ---------------------------------------------------------------------------
__global__ __launch_bounds__(128) void sched_kernel(
    const int* __restrict__ is_init,
    int* __restrict__ counts_g, int* __restrict__ offsets_g,
    unsigned* __restrict__ items_g)
{
    __shared__ int cnt[LSEQ];
    __shared__ int off[LSEQ];
    int tid = threadIdx.x;
    for (int i = tid; i < LSEQ; i += 128) cnt[i] = 0;
    __syncthreads();
    {
        int d = 0;
        for (int l = 0; l < LSEQ; l++) {
            int ii = is_init[tid * LSEQ + l];
            d = ii ? 0 : (l == 0 ? 0 : d + 1);
            atomicAdd(&cnt[d], 1);
        }
    }
    __syncthreads();
    if (tid == 0) {
        int acc = 0;
        for (int i = 0; i < LSEQ; i++) { off[i] = acc; acc += cnt[i]; }
    }
    __syncthreads();
    for (int i = tid; i < LSEQ; i += 128) {
        counts_g[i] = cnt[i];
        offsets_g[i] = off[i];
        cnt[i] = 0;   // reuse as cursor
    }
    __syncthreads();
    {
        int d = 0;
        for (int l = 0; l < LSEQ; l++) {
            int ii = is_init[tid * LSEQ + l];
            d = ii ? 0 : (l == 0 ? 0 : d + 1);
            int pos = off[d] + atomicAdd(&cnt[d], 1);
            items_g[pos] = (unsigned)((tid << 16) | l);
        }
    }
}

// ---------------------------------------------------------------------------
// phase: process all items at depth d. For each item (n,l):
//   gates = W_ih @ x[n,l] + W_hh @ h_in + biases ; h_new = GRU update
//   h_in: d>0 -> seq[n,l-1]; d==0 -> 0 if reset else h0[n]
// Tile: 64 items x 64 gate-columns per block, 256 threads, 16 items/thread.
// ---------------------------------------------------------------------------
__global__ __launch_bounds__(256) void phase_kernel(
    int d,
    const float* __restrict__ Wt_ih, const float* __restrict__ Wt_hh,
    const float* __restrict__ bias4,
    const int* __restrict__ counts, const int* __restrict__ offsets,
    const unsigned* __restrict__ items,
    const float* __restrict__ inp, const float* __restrict__ h0,
    const int* __restrict__ is_init,
    float* __restrict__ seq)
{
    const int count = counts[d];
    if (count == 0) return;
    const int base = offsets[d];
    const int jb = blockIdx.y;          // 0..7 -> 64 columns each
    const int tid = threadIdx.x;
    const int tx = tid & 63, ty = tid >> 6;
    const int j = jb * 64 + tx;

    __shared__ float xs[KC][68];
    __shared__ float hs[KC][68];

    const int ntiles = (count + TI - 1) / TI;
    for (int tile = blockIdx.x; tile < ntiles; tile += gridDim.x) {
        float ar[16], az[16], anx[16], anh[16];
        {
            float br = bias4[j], bz = bias4[512 + j];
            float bx = bias4[1024 + j], bh = bias4[1536 + j];
            #pragma unroll
            for (int i = 0; i < 16; i++) { ar[i] = br; az[i] = bz; anx[i] = bx; anh[i] = bh; }
        }

        for (int kc = 0; kc < HD; kc += KC) {
            __syncthreads();
            // stage A-tiles: x and h chunks, layout [k][item]
            for (int idx = tid; idx < TI * KC; idx += 256) {
                int k = idx & (KC - 1);
                int it = idx >> 4;
                int g = tile * TI + it;
                float xv = 0.f, hv = 0.f;
                if (g < count) {
                    unsigned w = items[base + g];
                    int n = (int)(w >> 16), l = (int)(w & 0xffff);
                    xv = inp[((size_t)(n * LSEQ + l)) * HD + kc + k];
                    if (d > 0) {
                        hv = seq[((size_t)(n * LSEQ + l - 1)) * HD + kc + k];
                    } else if (!is_init[n * LSEQ + l]) {
                        hv = h0[(size_t)n * HD + kc + k];
                    }
                }
                xs[k][it] = xv;
                hs[k][it] = hv;
            }
            __syncthreads();

            const float* wi = Wt_ih + (size_t)kc * G3;
            const float* wh = Wt_hh + (size_t)kc * G3;
            #pragma unroll 4
            for (int k = 0; k < KC; k++) {
                float wrx = wi[k * G3 + j];
                float wzx = wi[k * G3 + 512 + j];
                float wnx = wi[k * G3 + 1024 + j];
                float wrh = wh[k * G3 + j];
                float wzh = wh[k * G3 + 512 + j];
                float wnh = wh[k * G3 + 1024 + j];
                const float* xk = &xs[k][ty * 16];
                const float* hk = &hs[k][ty * 16];
                #pragma unroll
                for (int i = 0; i < 16; i++) {
                    float xv = xk[i], hv = hk[i];
                    ar[i]  += wrx * xv + wrh * hv;
                    az[i]  += wzx * xv + wzh * hv;
                    anx[i] += wnx * xv;
                    anh[i] += wnh * hv;
                }
            }
        }

        // epilogue: pointwise GRU update, write raw h into seq
        #pragma unroll
        for (int i = 0; i < 16; i++) {
            int g = tile * TI + ty * 16 + i;
            if (g >= count) continue;
            unsigned w = items[base + g];
            int n = (int)(w >> 16), l = (int)(w & 0xffff);
            float hv = 0.f;
            if (d > 0) {
                hv = seq[((size_t)(n * LSEQ + l - 1)) * HD + j];
            } else if (!is_init[n * LSEQ + l]) {
                hv = h0[(size_t)n * HD + j];
            }
            float r = 1.f / (1.f + __expf(-ar[i]));
            float z = 1.f / (1.f + __expf(-az[i]));
            float nn = tanhf(anx[i] + r * anh[i]);
            float hn = (1.f - z) * nn + z * hv;
            seq[((size_t)(n * LSEQ + l)) * HD + j] = hn;
        }
    }
}

// ---------------------------------------------------------------------------
// h_exp broadcast: out2[n,l,:] = seq[n,L-1,:]  (must run BEFORE LN overwrites)
// ---------------------------------------------------------------------------
__global__ __launch_bounds__(256) void hexp_kernel(
    const float* __restrict__ seq, float* __restrict__ out2)
{
    size_t idx = (size_t)blockIdx.x * 256 + threadIdx.x;
    if (idx >= (size_t)NB * LSEQ * HD) return;
    int n = (int)(idx / (LSEQ * HD));
    int j = (int)(idx & (HD - 1));
    out2[idx] = seq[((size_t)n * LSEQ + (LSEQ - 1)) * HD + j];
}

// ---------------------------------------------------------------------------
// LayerNorm in place over seq: out = LN(seq + inp) * gamma + beta
// one block per (n,l) row
// ---------------------------------------------------------------------------
__global__ __launch_bounds__(256) void ln_kernel(
    const float* __restrict__ inp,
    const float* __restrict__ gamma, const float* __restrict__ beta,
    float* __restrict__ seq)
{
    size_t row = blockIdx.x;
    int tid = threadIdx.x;
    const float* yrow = seq + row * HD;
    const float* xrow = inp + row * HD;
    float a = yrow[tid] + xrow[tid];
    float b = yrow[tid + 256] + xrow[tid + 256];
    float s = a + b, ss = a * a + b * b;
    #pragma unroll
    for (int m = 1; m < 64; m <<= 1) {
        s  += __shfl_xor(s, m, 64);
        ss += __shfl_xor(ss, m, 64);
    }
    __shared__ float ps[4], pss[4];
    int w = tid >> 6;
    if ((tid & 63) == 0) { ps[w] = s; pss[w] = ss; }
    __syncthreads();
    s  = ps[0] + ps[1] + ps[2] + ps[3];
    ss = pss[0] + pss[1] + pss[2] + pss[3];
    float mu = s * (1.f / 512.f);
    float var = ss * (1.f / 512.f) - mu * mu;
    float inv = rsqrtf(var + 1e-5f);
    float* orow = seq + row * HD;
    orow[tid]       = (a - mu) * inv * gamma[tid] + beta[tid];
    orow[tid + 256] = (b - mu) * inv * gamma[tid + 256] + beta[tid + 256];
}

// ---------------------------------------------------------------------------
extern "C" void kernel_launch(void* const* d_in, const int* in_sizes, int n_in,
                              void* d_out, int out_size, void* d_ws, size_t ws_size,
                              hipStream_t stream)
{
    const float* inp   = (const float*)d_in[0];
    const float* h0    = (const float*)d_in[1];
    const int*  is_ini = (const int*)d_in[2];
    const float* W_ih  = (const float*)d_in[3];
    const float* W_hh  = (const float*)d_in[4];
    const float* b_ih  = (const float*)d_in[5];
    const float* b_hh  = (const float*)d_in[6];
    const float* gamma = (const float*)d_in[7];
    const float* beta  = (const float*)d_in[8];

    float* out  = (float*)d_out;
    float* seq  = out;                             // first N*L*H: raw h, then LN in place
    float* out2 = out + (size_t)NB * LSEQ * HD;    // h_exp broadcast

    float* Wt_ih = (float*)d_ws;
    float* Wt_hh = Wt_ih + (size_t)HD * G3;
    float* bias4 = Wt_hh + (size_t)HD * G3;
    int* counts  = (int*)(bias4 + 2048);
    int* offsets = counts + LSEQ;
    unsigned* items = (unsigned*)(offsets + LSEQ);
    // total ws use ~6.6 MB

    prep_kernel<<<(HD * G3 + 255) / 256, 256, 0, stream>>>(
        W_ih, W_hh, b_ih, b_hh, Wt_ih, Wt_hh, bias4);

    sched_kernel<<<1, 128, 0, stream>>>(is_ini, counts, offsets, items);

    for (int d = 0; d < MAX_DEPTH; d++) {
        phase_kernel<<<dim3(512, 8), 256, 0, stream>>>(
            d, Wt_ih, Wt_hh, bias4, counts, offsets, items,
            inp, h0, is_ini, seq);
    }

    hexp_kernel<<<(int)(((size_t)NB * LSEQ * HD + 255) / 256), 256, 0, stream>>>(seq, out2);

    ln_kernel<<<NB * LSEQ, 256, 0, stream>>>(inp, gamma, beta, seq);
}

// Round 3
// 9774.748 us; speedup vs baseline: 1.0092x; 1.0092x over previous
//
#include <hip/hip_runtime.h>
#include <hip/hip_bf16.h>

#define NB 128
#define LSEQ 512
#define HD 512
#define G3 1536
#define TI 64
#define KC 16
#define MAX_DEPTH 64

// ---------------------------------------------------------------------------
// prep: transpose W_ih, W_hh -> [k][3H], combine biases
// ---------------------------------------------------------------------------
__global__ __launch_bounds__(256) void prep_kernel(
    const float* __restrict__ W_ih, const float* __restrict__ W_hh,
    const float* __restrict__ b_ih, const float* __restrict__ b_hh,
    float* __restrict__ Wt_ih, float* __restrict__ Wt_hh,
    float* __restrict__ bias4)
{
    int idx = blockIdx.x * 256 + threadIdx.x;
    if (idx < HD * G3) {
        int k = idx / G3, g = idx % G3;
        Wt_ih[idx] = W_ih[g * HD + k];
        Wt_hh[idx] = W_hh[g * HD + k];
    }
    if (idx < HD) {
        bias4[idx]        = b_ih[idx]        + b_hh[idx];         // r
        bias4[512 + idx]  = b_ih[512 + idx]  + b_hh[512 + idx];   // z
        bias4[1024 + idx] = b_ih[1024 + idx];                     // n (x side)
        bias4[1536 + idx] = b_hh[1024 + idx];                     // n (h side)
    }
}

// ---------------------------------------------------------------------------
// sched: compute depth of every (n,l), bucket items by depth.
// depth = distance since last is_initial==1 (is_initial applies at step start).
// One block, 128 threads (one per batch row).
// ---------------------------------------------------------------------------
__global__ __launch_bounds__(128) void sched_kernel(
    const int* __restrict__ is_init,
    int* __restrict__ counts_g, int* __restrict__ offsets_g,
    unsigned* __restrict__ items_g)
{
    __shared__ int cnt[LSEQ];
    __shared__ int off[LSEQ];
    int tid = threadIdx.x;
    for (int i = tid; i < LSEQ; i += 128) cnt[i] = 0;
    __syncthreads();
    {
        int d = 0;
        for (int l = 0; l < LSEQ; l++) {
            int ii = is_init[tid * LSEQ + l];
            d = ii ? 0 : (l == 0 ? 0 : d + 1);
            atomicAdd(&cnt[d], 1);
        }
    }
    __syncthreads();
    if (tid == 0) {
        int acc = 0;
        for (int i = 0; i < LSEQ; i++) { off[i] = acc; acc += cnt[i]; }
    }
    __syncthreads();
    for (int i = tid; i < LSEQ; i += 128) {
        counts_g[i] = cnt[i];
        offsets_g[i] = off[i];
        cnt[i] = 0;   // reuse as cursor
    }
    __syncthreads();
    {
        int d = 0;
        for (int l = 0; l < LSEQ; l++) {
            int ii = is_init[tid * LSEQ + l];
            d = ii ? 0 : (l == 0 ? 0 : d + 1);
            int pos = off[d] + atomicAdd(&cnt[d], 1);
            items_g[pos] = (unsigned)((tid << 16) | l);
        }
    }
}

// ---------------------------------------------------------------------------
// phase: process all items at depth d. For each item (n,l):
//   gates = W_ih @ x[n,l] + W_hh @ h_in + biases ; h_new = GRU update
//   h_in: d>0 -> seq[n,l-1]; d==0 -> 0 if reset else h0[n]
// Tile: 64 items x 64 gate-columns per block, 256 threads, 16 items/thread.
// ---------------------------------------------------------------------------
__global__ __launch_bounds__(256) void phase_kernel(
    int d,
    const float* __restrict__ Wt_ih, const float* __restrict__ Wt_hh,
    const float* __restrict__ bias4,
    const int* __restrict__ counts, const int* __restrict__ offsets,
    const unsigned* __restrict__ items,
    const float* __restrict__ inp, const float* __restrict__ h0,
    const int* __restrict__ is_init,
    float* __restrict__ seq)
{
    const int count = counts[d];
    if (count == 0) return;
    const int base = offsets[d];
    const int jb = blockIdx.y;          // 0..7 -> 64 columns each
    const int tid = threadIdx.x;
    const int tx = tid & 63, ty = tid >> 6;
    const int j = jb * 64 + tx;

    __shared__ float xs[KC][68];
    __shared__ float hs[KC][68];

    const int ntiles = (count + TI - 1) / TI;
    for (int tile = blockIdx.x; tile < ntiles; tile += gridDim.x) {
        float ar[16], az[16], anx[16], anh[16];
        {
            float br = bias4[j], bz = bias4[512 + j];
            float bx = bias4[1024 + j], bh = bias4[1536 + j];
            #pragma unroll
            for (int i = 0; i < 16; i++) { ar[i] = br; az[i] = bz; anx[i] = bx; anh[i] = bh; }
        }

        for (int kc = 0; kc < HD; kc += KC) {
            __syncthreads();
            // stage A-tiles: x and h chunks, layout [k][item]
            for (int idx = tid; idx < TI * KC; idx += 256) {
                int k = idx & (KC - 1);
                int it = idx >> 4;
                int g = tile * TI + it;
                float xv = 0.f, hv = 0.f;
                if (g < count) {
                    unsigned w = items[base + g];
                    int n = (int)(w >> 16), l = (int)(w & 0xffff);
                    xv = inp[((size_t)(n * LSEQ + l)) * HD + kc + k];
                    if (d > 0) {
                        hv = seq[((size_t)(n * LSEQ + l - 1)) * HD + kc + k];
                    } else if (!is_init[n * LSEQ + l]) {
                        hv = h0[(size_t)n * HD + kc + k];
                    }
                }
                xs[k][it] = xv;
                hs[k][it] = hv;
            }
            __syncthreads();

            const float* wi = Wt_ih + (size_t)kc * G3;
            const float* wh = Wt_hh + (size_t)kc * G3;
            #pragma unroll 4
            for (int k = 0; k < KC; k++) {
                float wrx = wi[k * G3 + j];
                float wzx = wi[k * G3 + 512 + j];
                float wnx = wi[k * G3 + 1024 + j];
                float wrh = wh[k * G3 + j];
                float wzh = wh[k * G3 + 512 + j];
                float wnh = wh[k * G3 + 1024 + j];
                const float* xk = &xs[k][ty * 16];
                const float* hk = &hs[k][ty * 16];
                #pragma unroll
                for (int i = 0; i < 16; i++) {
                    float xv = xk[i], hv = hk[i];
                    ar[i]  += wrx * xv + wrh * hv;
                    az[i]  += wzx * xv + wzh * hv;
                    anx[i] += wnx * xv;
                    anh[i] += wnh * hv;
                }
            }
        }

        // epilogue: pointwise GRU update, write raw h into seq
        #pragma unroll
        for (int i = 0; i < 16; i++) {
            int g = tile * TI + ty * 16 + i;
            if (g >= count) continue;
            unsigned w = items[base + g];
            int n = (int)(w >> 16), l = (int)(w & 0xffff);
            float hv = 0.f;
            if (d > 0) {
                hv = seq[((size_t)(n * LSEQ + l - 1)) * HD + j];
            } else if (!is_init[n * LSEQ + l]) {
                hv = h0[(size_t)n * HD + j];
            }
            float r = 1.f / (1.f + __expf(-ar[i]));
            float z = 1.f / (1.f + __expf(-az[i]));
            float nn = tanhf(anx[i] + r * anh[i]);
            float hn = (1.f - z) * nn + z * hv;
            seq[((size_t)(n * LSEQ + l)) * HD + j] = hn;
        }
    }
}

// ---------------------------------------------------------------------------
// h_exp broadcast: out2[n,l,:] = seq[n,L-1,:]  (must run BEFORE LN overwrites)
// ---------------------------------------------------------------------------
__global__ __launch_bounds__(256) void hexp_kernel(
    const float* __restrict__ seq, float* __restrict__ out2)
{
    size_t idx = (size_t)blockIdx.x * 256 + threadIdx.x;
    if (idx >= (size_t)NB * LSEQ * HD) return;
    int n = (int)(idx / (LSEQ * HD));
    int j = (int)(idx & (HD - 1));
    out2[idx] = seq[((size_t)n * LSEQ + (LSEQ - 1)) * HD + j];
}

// ---------------------------------------------------------------------------
// LayerNorm in place over seq: out = LN(seq + inp) * gamma + beta
// one block per (n,l) row
// ---------------------------------------------------------------------------
__global__ __launch_bounds__(256) void ln_kernel(
    const float* __restrict__ inp,
    const float* __restrict__ gamma, const float* __restrict__ beta,
    float* __restrict__ seq)
{
    size_t row = blockIdx.x;
    int tid = threadIdx.x;
    const float* yrow = seq + row * HD;
    const float* xrow = inp + row * HD;
    float a = yrow[tid] + xrow[tid];
    float b = yrow[tid + 256] + xrow[tid + 256];
    float s = a + b, ss = a * a + b * b;
    #pragma unroll
    for (int m = 1; m < 64; m <<= 1) {
        s  += __shfl_xor(s, m, 64);
        ss += __shfl_xor(ss, m, 64);
    }
    __shared__ float ps[4], pss[4];
    int w = tid >> 6;
    if ((tid & 63) == 0) { ps[w] = s; pss[w] = ss; }
    __syncthreads();
    s  = ps[0] + ps[1] + ps[2] + ps[3];
    ss = pss[0] + pss[1] + pss[2] + pss[3];
    float mu = s * (1.f / 512.f);
    float var = ss * (1.f / 512.f) - mu * mu;
    float inv = rsqrtf(var + 1e-5f);
    float* orow = seq + row * HD;
    orow[tid]       = (a - mu) * inv * gamma[tid] + beta[tid];
    orow[tid + 256] = (b - mu) * inv * gamma[tid + 256] + beta[tid + 256];
}

// ---------------------------------------------------------------------------
extern "C" void kernel_launch(void* const* d_in, const int* in_sizes, int n_in,
                              void* d_out, int out_size, void* d_ws, size_t ws_size,
                              hipStream_t stream)
{
    const float* inp   = (const float*)d_in[0];
    const float* h0    = (const float*)d_in[1];
    const int*  is_ini = (const int*)d_in[2];
    const float* W_ih  = (const float*)d_in[3];
    const float* W_hh  = (const float*)d_in[4];
    const float* b_ih  = (const float*)d_in[5];
    const float* b_hh  = (const float*)d_in[6];
    const float* gamma = (const float*)d_in[7];
    const float* beta  = (const float*)d_in[8];

    float* out  = (float*)d_out;
    float* seq  = out;                             // first N*L*H: raw h, then LN in place
    float* out2 = out + (size_t)NB * LSEQ * HD;    // h_exp broadcast

    float* Wt_ih = (float*)d_ws;
    float* Wt_hh = Wt_ih + (size_t)HD * G3;
    float* bias4 = Wt_hh + (size_t)HD * G3;
    int* counts  = (int*)(bias4 + 2048);
    int* offsets = counts + LSEQ;
    unsigned* items = (unsigned*)(offsets + LSEQ);
    // total ws use ~6.6 MB

    prep_kernel<<<(HD * G3 + 255) / 256, 256, 0, stream>>>(
        W_ih, W_hh, b_ih, b_hh, Wt_ih, Wt_hh, bias4);

    sched_kernel<<<1, 128, 0, stream>>>(is_ini, counts, offsets, items);

    for (int d = 0; d < MAX_DEPTH; d++) {
        phase_kernel<<<dim3(512, 8), 256, 0, stream>>>(
            d, Wt_ih, Wt_hh, bias4, counts, offsets, items,
            inp, h0, is_ini, seq);
    }

    hexp_kernel<<<(int)(((size_t)NB * LSEQ * HD + 255) / 256), 256, 0, stream>>>(seq, out2);

    ln_kernel<<<NB * LSEQ, 256, 0, stream>>>(inp, gamma, beta, seq);
}

// Round 4
// 1480.723 us; speedup vs baseline: 6.6618x; 6.6013x over previous
//
#include <hip/hip_runtime.h>
#include <hip/hip_bf16.h>

#define NB 128
#define LSEQ 512
#define HD 512
#define MAX_DEPTH 64
#define MT 32

typedef __attribute__((ext_vector_type(8))) short bf16x8;
typedef __attribute__((ext_vector_type(4))) float f32x4;

static __device__ __forceinline__ unsigned short f2b(float x) {
    union { __hip_bfloat16 b; unsigned short u; } cv;
    cv.b = __float2bfloat16(x);
    return cv.u;
}

// ---------------------------------------------------------------------------
// bias_kernel: combined biases. r: b_ih+b_hh ; z: b_ih+b_hh ; nx: b_ih ; nh: b_hh
// ---------------------------------------------------------------------------
__global__ __launch_bounds__(256) void bias_kernel(
    const float* __restrict__ b_ih, const float* __restrict__ b_hh,
    float* __restrict__ bias4)
{
    int i = blockIdx.x * 256 + threadIdx.x;
    if (i >= HD) return;
    bias4[i]        = b_ih[i]        + b_hh[i];
    bias4[512 + i]  = b_ih[512 + i]  + b_hh[512 + i];
    bias4[1024 + i] = b_ih[1024 + i];
    bias4[1536 + i] = b_hh[1024 + i];
}

// ---------------------------------------------------------------------------
// pack_kernel: W_ih/W_hh [1536][512] row-major -> MFMA-frag-major bf16 packs.
// B-frag (16x16x32): lane l holds B[k=kc*32+(l>>4)*8+j][col=ct*16+(l&15)], j=0..7.
// Pack element index: ((ct*16+kc)*64 + lane)*8 + j
// ---------------------------------------------------------------------------
__global__ __launch_bounds__(256) void pack_kernel(
    const float* __restrict__ W_ih, const float* __restrict__ W_hh,
    unsigned short* __restrict__ Xpack, unsigned short* __restrict__ Hpack)
{
    int idx = blockIdx.x * 256 + threadIdx.x;   // = g*512 + k
    if (idx >= 1536 * 512) return;
    int g = idx >> 9, k = idx & 511;
    int ct = g >> 4, lane_lo = g & 15;
    int kc = k >> 5, kin = k & 31;
    int lane = (kin >> 3) * 16 + lane_lo;
    int j = kin & 7;
    int p = ((ct * 16 + kc) * 64 + lane) * 8 + j;
    Xpack[p] = f2b(W_ih[idx]);
    Hpack[p] = f2b(W_hh[idx]);
}

// ---------------------------------------------------------------------------
// sched: bucket (n,l) items by depth-within-episode.
// ---------------------------------------------------------------------------
__global__ __launch_bounds__(128) void sched_kernel(
    const int* __restrict__ is_init,
    int* __restrict__ counts_g, int* __restrict__ offsets_g,
    unsigned* __restrict__ items_g)
{
    __shared__ int cnt[LSEQ];
    __shared__ int off[LSEQ];
    int tid = threadIdx.x;
    for (int i = tid; i < LSEQ; i += 128) cnt[i] = 0;
    __syncthreads();
    {
        int d = 0;
        for (int l = 0; l < LSEQ; l++) {
            int ii = is_init[tid * LSEQ + l];
            d = ii ? 0 : (l == 0 ? 0 : d + 1);
            atomicAdd(&cnt[d], 1);
        }
    }
    __syncthreads();
    if (tid == 0) {
        int acc = 0;
        for (int i = 0; i < LSEQ; i++) { off[i] = acc; acc += cnt[i]; }
    }
    __syncthreads();
    for (int i = tid; i < LSEQ; i += 128) {
        counts_g[i] = cnt[i];
        offsets_g[i] = off[i];
        cnt[i] = 0;
    }
    __syncthreads();
    {
        int d = 0;
        for (int l = 0; l < LSEQ; l++) {
            int ii = is_init[tid * LSEQ + l];
            d = ii ? 0 : (l == 0 ? 0 : d + 1);
            int pos = off[d] + atomicAdd(&cnt[d], 1);
            items_g[pos] = (unsigned)((tid << 16) | l);
        }
    }
}

// ---------------------------------------------------------------------------
// phase: MFMA bf16 gate GEMM + fused GRU epilogue for all items at depth d.
// 8 waves, 32 items/tile. Wave w owns cols [64w,64w+64) of each gate group.
// ---------------------------------------------------------------------------
__global__ __launch_bounds__(512, 2) void phase_kernel(
    int d,
    const unsigned short* __restrict__ Xpack, const unsigned short* __restrict__ Hpack,
    const float* __restrict__ bias4,
    const int* __restrict__ counts, const int* __restrict__ offsets,
    const unsigned* __restrict__ items,
    const float* __restrict__ inp, const float* __restrict__ h0,
    const int* __restrict__ is_init,
    float* __restrict__ seq)
{
    const int count = counts[d];
    if (count == 0) return;
    const int base = offsets[d];
    const int tid = threadIdx.x;
    const int w = tid >> 6, lane = tid & 63;
    const int l15 = lane & 15, lhi = lane >> 4;

    __shared__ unsigned short Xt[MT * 512];   // 32 KB, XOR-swizzled bf16
    __shared__ unsigned short Ht[MT * 512];   // 32 KB

    const float* hbase = (d > 0) ? seq : h0;

    // hoisted per-wave bias registers (cols fixed across tiles)
    const int cb = w * 64;
    float br[4], bz[4], bnx[4], bnh[4];
    #pragma unroll
    for (int f = 0; f < 4; ++f) {
        int cf = cb + f * 16 + l15;
        br[f]  = bias4[cf];
        bz[f]  = bias4[512 + cf];
        bnx[f] = bias4[1024 + cf];
        bnh[f] = bias4[1536 + cf];
    }

    // per-lane pack base (lane-contiguous dwordx4 frags)
    const unsigned short* xb = Xpack + lane * 8;
    const unsigned short* hb = Hpack + lane * 8;

    const int ntiles = (count + MT - 1) / MT;
    for (int tile = blockIdx.x; tile < ntiles; tile += gridDim.x) {
        __syncthreads();   // protect LDS tiles from previous iteration's readers

        // ---- stage X,H tiles (fp32 -> bf16, swizzled) ----
        for (int idx = tid; idx < MT * 128; idx += 512) {
            int row = idx >> 7;
            int k = (idx & 127) << 2;
            int g = tile * MT + row;
            float4 xv = make_float4(0.f, 0.f, 0.f, 0.f);
            float4 hv = make_float4(0.f, 0.f, 0.f, 0.f);
            if (g < count) {
                unsigned wv = items[base + g];
                int n = (int)(wv >> 16), l = (int)(wv & 0xffff);
                int oo = (n * LSEQ + l) * HD;
                xv = *(const float4*)(inp + oo + k);
                if (d > 0) {
                    hv = *(const float4*)(hbase + (oo - HD) + k);
                } else if (!is_init[n * LSEQ + l]) {
                    hv = *(const float4*)(hbase + n * HD + k);
                }
            }
            unsigned x01 = (unsigned)f2b(xv.x) | ((unsigned)f2b(xv.y) << 16);
            unsigned x23 = (unsigned)f2b(xv.z) | ((unsigned)f2b(xv.w) << 16);
            unsigned h01 = (unsigned)f2b(hv.x) | ((unsigned)f2b(hv.y) << 16);
            unsigned h23 = (unsigned)f2b(hv.z) | ((unsigned)f2b(hv.w) << 16);
            int byte = (row << 10) + (k << 1);
            byte ^= (row & 7) << 4;
            *(uint2*)((char*)Xt + byte) = make_uint2(x01, x23);
            *(uint2*)((char*)Ht + byte) = make_uint2(h01, h23);
        }
        __syncthreads();

        f32x4 accR[2][4], accZ[2][4], accNX[2][4], accNH[2][4];
        #pragma unroll
        for (int m = 0; m < 2; ++m)
        #pragma unroll
        for (int f = 0; f < 4; ++f) {
            accR[m][f]  = (f32x4){0.f, 0.f, 0.f, 0.f};
            accZ[m][f]  = (f32x4){0.f, 0.f, 0.f, 0.f};
            accNX[m][f] = (f32x4){0.f, 0.f, 0.f, 0.f};
            accNH[m][f] = (f32x4){0.f, 0.f, 0.f, 0.f};
        }

        // A-frag swizzled LDS offsets (row0 = l15, row1 = 16+l15: same XOR bits)
        // X half: C += X @ Wih  (accumulates r, z, nx)
        for (int kc = 0; kc < 16; ++kc) {
            int ka = (kc << 5) + (lhi << 3);
            int b0 = ((l15 << 10) + (ka << 1)) ^ ((l15 & 7) << 4);
            bf16x8 a0 = *(const bf16x8*)((const char*)Xt + b0);
            bf16x8 a1 = *(const bf16x8*)((const char*)Xt + b0 + 16384);
            #pragma unroll
            for (int f = 0; f < 4; ++f) {
                bf16x8 bR = *(const bf16x8*)(xb + (((4 * w + f) * 16 + kc) << 9));
                bf16x8 bZ = *(const bf16x8*)(xb + (((32 + 4 * w + f) * 16 + kc) << 9));
                bf16x8 bN = *(const bf16x8*)(xb + (((64 + 4 * w + f) * 16 + kc) << 9));
                accR[0][f]  = __builtin_amdgcn_mfma_f32_16x16x32_bf16(a0, bR, accR[0][f], 0, 0, 0);
                accR[1][f]  = __builtin_amdgcn_mfma_f32_16x16x32_bf16(a1, bR, accR[1][f], 0, 0, 0);
                accZ[0][f]  = __builtin_amdgcn_mfma_f32_16x16x32_bf16(a0, bZ, accZ[0][f], 0, 0, 0);
                accZ[1][f]  = __builtin_amdgcn_mfma_f32_16x16x32_bf16(a1, bZ, accZ[1][f], 0, 0, 0);
                accNX[0][f] = __builtin_amdgcn_mfma_f32_16x16x32_bf16(a0, bN, accNX[0][f], 0, 0, 0);
                accNX[1][f] = __builtin_amdgcn_mfma_f32_16x16x32_bf16(a1, bN, accNX[1][f], 0, 0, 0);
            }
        }
        // H half: C += H @ Whh  (accumulates r, z, nh)
        for (int kc = 0; kc < 16; ++kc) {
            int ka = (kc << 5) + (lhi << 3);
            int b0 = ((l15 << 10) + (ka << 1)) ^ ((l15 & 7) << 4);
            bf16x8 a0 = *(const bf16x8*)((const char*)Ht + b0);
            bf16x8 a1 = *(const bf16x8*)((const char*)Ht + b0 + 16384);
            #pragma unroll
            for (int f = 0; f < 4; ++f) {
                bf16x8 bR = *(const bf16x8*)(hb + (((4 * w + f) * 16 + kc) << 9));
                bf16x8 bZ = *(const bf16x8*)(hb + (((32 + 4 * w + f) * 16 + kc) << 9));
                bf16x8 bN = *(const bf16x8*)(hb + (((64 + 4 * w + f) * 16 + kc) << 9));
                accR[0][f]  = __builtin_amdgcn_mfma_f32_16x16x32_bf16(a0, bR, accR[0][f], 0, 0, 0);
                accR[1][f]  = __builtin_amdgcn_mfma_f32_16x16x32_bf16(a1, bR, accR[1][f], 0, 0, 0);
                accZ[0][f]  = __builtin_amdgcn_mfma_f32_16x16x32_bf16(a0, bZ, accZ[0][f], 0, 0, 0);
                accZ[1][f]  = __builtin_amdgcn_mfma_f32_16x16x32_bf16(a1, bZ, accZ[1][f], 0, 0, 0);
                accNH[0][f] = __builtin_amdgcn_mfma_f32_16x16x32_bf16(a0, bN, accNH[0][f], 0, 0, 0);
                accNH[1][f] = __builtin_amdgcn_mfma_f32_16x16x32_bf16(a1, bN, accNH[1][f], 0, 0, 0);
            }
        }

        // ---- epilogue: GRU pointwise, lane-local (C/D: row=(l>>4)*4+q, col=l&15) ----
        #pragma unroll
        for (int m = 0; m < 2; ++m)
        #pragma unroll
        for (int q = 0; q < 4; ++q) {
            int item = m * 16 + lhi * 4 + q;
            int g = tile * MT + item;
            if (g >= count) continue;
            unsigned wv = items[base + g];
            int n = (int)(wv >> 16), l = (int)(wv & 0xffff);
            int oo = (n * LSEQ + l) * HD;
            int ho;
            if (d > 0) ho = oo - HD;
            else ho = is_init[n * LSEQ + l] ? -1 : n * HD;
            #pragma unroll
            for (int f = 0; f < 4; ++f) {
                int cf = cb + f * 16 + l15;
                float hp = (ho >= 0) ? hbase[ho + cf] : 0.f;
                float r = 1.f / (1.f + __expf(-(accR[m][f][q] + br[f])));
                float z = 1.f / (1.f + __expf(-(accZ[m][f][q] + bz[f])));
                float nn = tanhf(accNX[m][f][q] + bnx[f] + r * (accNH[m][f][q] + bnh[f]));
                seq[oo + cf] = (1.f - z) * nn + z * hp;
            }
        }
    }
}

// ---------------------------------------------------------------------------
// h_exp broadcast (before LN overwrites seq): out2[n,l,:] = seq[n,L-1,:]
// ---------------------------------------------------------------------------
__global__ __launch_bounds__(256) void hexp_kernel(
    const float* __restrict__ seq, float* __restrict__ out2)
{
    size_t idx = (size_t)blockIdx.x * 256 + threadIdx.x;   // float4 units
    if (idx >= (size_t)NB * LSEQ * HD / 4) return;
    int per_n = LSEQ * HD / 4;
    int n = (int)(idx / per_n);
    int c4 = (int)(idx & (HD / 4 - 1));
    float4 v = *(const float4*)(seq + ((size_t)n * LSEQ + (LSEQ - 1)) * HD + c4 * 4);
    *(float4*)(out2 + idx * 4) = v;
}

// ---------------------------------------------------------------------------
// LayerNorm in place: seq = LN(seq + inp) * gamma + beta
// ---------------------------------------------------------------------------
__global__ __launch_bounds__(256) void ln_kernel(
    const float* __restrict__ inp,
    const float* __restrict__ gamma, const float* __restrict__ beta,
    float* __restrict__ seq)
{
    size_t row = blockIdx.x;
    int tid = threadIdx.x;
    const float* yrow = seq + row * HD;
    const float* xrow = inp + row * HD;
    float a = yrow[tid] + xrow[tid];
    float b = yrow[tid + 256] + xrow[tid + 256];
    float s = a + b, ss = a * a + b * b;
    #pragma unroll
    for (int m = 1; m < 64; m <<= 1) {
        s  += __shfl_xor(s, m, 64);
        ss += __shfl_xor(ss, m, 64);
    }
    __shared__ float ps[4], pss[4];
    int w = tid >> 6;
    if ((tid & 63) == 0) { ps[w] = s; pss[w] = ss; }
    __syncthreads();
    s  = ps[0] + ps[1] + ps[2] + ps[3];
    ss = pss[0] + pss[1] + pss[2] + pss[3];
    float mu = s * (1.f / 512.f);
    float var = ss * (1.f / 512.f) - mu * mu;
    float inv = rsqrtf(var + 1e-5f);
    float* orow = seq + row * HD;
    orow[tid]       = (a - mu) * inv * gamma[tid] + beta[tid];
    orow[tid + 256] = (b - mu) * inv * gamma[tid + 256] + beta[tid + 256];
}

// ---------------------------------------------------------------------------
extern "C" void kernel_launch(void* const* d_in, const int* in_sizes, int n_in,
                              void* d_out, int out_size, void* d_ws, size_t ws_size,
                              hipStream_t stream)
{
    const float* inp   = (const float*)d_in[0];
    const float* h0    = (const float*)d_in[1];
    const int*  is_ini = (const int*)d_in[2];
    const float* W_ih  = (const float*)d_in[3];
    const float* W_hh  = (const float*)d_in[4];
    const float* b_ih  = (const float*)d_in[5];
    const float* b_hh  = (const float*)d_in[6];
    const float* gamma = (const float*)d_in[7];
    const float* beta  = (const float*)d_in[8];

    float* out  = (float*)d_out;
    float* seq  = out;                             // raw h, then LN in place
    float* out2 = out + (size_t)NB * LSEQ * HD;    // h_exp broadcast

    unsigned short* Xpack = (unsigned short*)d_ws;           // 1.5 MB
    unsigned short* Hpack = Xpack + 1536 * 512;              // 1.5 MB
    float* bias4 = (float*)(Hpack + 1536 * 512);
    int* counts  = (int*)(bias4 + 2048);
    int* offsets = counts + LSEQ;
    unsigned* items = (unsigned*)(offsets + LSEQ);           // 256 KB

    bias_kernel<<<2, 256, 0, stream>>>(b_ih, b_hh, bias4);
    pack_kernel<<<(1536 * 512 + 255) / 256, 256, 0, stream>>>(W_ih, W_hh, Xpack, Hpack);
    sched_kernel<<<1, 128, 0, stream>>>(is_ini, counts, offsets, items);

    for (int d = 0; d < MAX_DEPTH; d++) {
        int gsz = 2048 >> d;
        if (gsz > 1024) gsz = 1024;
        if (gsz < 8) gsz = 8;
        phase_kernel<<<gsz, 512, 0, stream>>>(
            d, Xpack, Hpack, bias4, counts, offsets, items,
            inp, h0, is_ini, seq);
    }

    hexp_kernel<<<(int)(((size_t)NB * LSEQ * HD / 4 + 255) / 256), 256, 0, stream>>>(seq, out2);
    ln_kernel<<<NB * LSEQ, 256, 0, stream>>>(inp, gamma, beta, seq);
}